// Round 3
// baseline (347.631 us; speedup 1.0000x reference)
//
#include <hip/hip_runtime.h>
#include <stdint.h>

// B=2, T=2048, DIM=1024, H=16, HD=64. Device tensors are FLOAT32 (per the
// reference dtypes; confirmed by npz sizes: 31MB in / 15.5MB out = f32).
// out = causal_attn(x@wq^T, x@wk^T, x@wv^T) @ wo^T, scale 1/8.
// Internally: convert inputs to bf16 once, run bf16 MFMA pipeline, write f32.
//
// ws (40MB): xb@0 (8MB), wb@8MB (4x2MB: wq,wk,wv,wo), Kb@16MB, Vb@24MB,
// Ob@32MB. Qb (bf16, 8MB) lives in d_out's first half; dead before final GEMM.

#define T_SEQ 2048

typedef unsigned short u16;
typedef __attribute__((ext_vector_type(8))) __bf16 bf16x8;   // MFMA A/B frag
typedef __attribute__((ext_vector_type(8))) short  s16x8;    // raw 16B move
typedef __attribute__((ext_vector_type(4))) float  f32x4;    // MFMA C/D frag

#define NEG_BIG (-30000.0f)   // << min possible score; exp-safe sentinel

__device__ __forceinline__ u16 f2bf(float x) {
    union { float f; unsigned u; } c; c.f = x;
    return (u16)((c.u + 0x7fffu + ((c.u >> 16) & 1u)) >> 16);
}

__device__ __forceinline__ void gload_lds16(const void* g, void* l) {
    __builtin_amdgcn_global_load_lds(
        (const __attribute__((address_space(1))) void*)g,
        (__attribute__((address_space(3))) void*)l, 16, 0, 0);
}

__device__ __forceinline__ void storeC(u16* p, float v)   { *p = f2bf(v); }
__device__ __forceinline__ void storeC(float* p, float v) { *p = v; }

// ---------------------------------------------------------------------------
// f32 -> bf16 conversion, 4 elems/thread
// ---------------------------------------------------------------------------
__global__ __launch_bounds__(256) void cvt_f32_bf16(
    const float* __restrict__ src, u16* __restrict__ dst, int n4)
{
    int i = blockIdx.x * 256 + threadIdx.x;
    if (i < n4) {
        float4 v = ((const float4*)src)[i];
        ushort4 o;
        o.x = f2bf(v.x); o.y = f2bf(v.y); o.z = f2bf(v.z); o.w = f2bf(v.w);
        ((ushort4*)dst)[i] = o;
    }
}

// ---------------------------------------------------------------------------
// GEMM: C[4096][1024] = A[4096][1024] @ W[1024][1024]^T (both K-contiguous,
// bf16). m97 structure: 128x128 tile, BK=64, 4 waves, linear LDS,
// global_load_lds width=16. W = Wb + z*1M elems; C selected by z.
// ---------------------------------------------------------------------------
template <typename OutT>
__global__ __launch_bounds__(256) void gemm_bt(
    const u16* __restrict__ A, const u16* __restrict__ Wb,
    OutT* __restrict__ C0, OutT* __restrict__ C1, OutT* __restrict__ C2)
{
    __shared__ __align__(16) char As[128 * 128];   // 128 rows x 64 bf16
    __shared__ __align__(16) char Bs[128 * 128];

    const u16* W = Wb + (size_t)blockIdx.z * 1048576u;
    OutT* Cz = blockIdx.z == 0 ? C0 : (blockIdx.z == 1 ? C1 : C2);

    const int tid = threadIdx.x;
    const int w = tid >> 6, l = tid & 63;
    const int wy = w >> 1, wx = w & 1;
    const int bm = blockIdx.y * 128, bn = blockIdx.x * 128;

    f32x4 acc[4][4];
#pragma unroll
    for (int m = 0; m < 4; m++)
#pragma unroll
        for (int n = 0; n < 4; n++) acc[m][n] = (f32x4){0.f, 0.f, 0.f, 0.f};

    const int lrow = l >> 3;       // row within 8-row chunk
    const int lslot = l & 7;       // 16B slot within 128B row

    for (int kt = 0; kt < 16; ++kt) {              // K = 16 * 64
#pragma unroll
        for (int c = 0; c < 4; ++c) {              // wave stages 4x1KB of A and B
            int ch = w * 4 + c;
            int row = ch * 8 + lrow;
            const char* ga = (const char*)A
                + ((size_t)(bm + row) * 1024 + kt * 64) * 2 + lslot * 16;
            gload_lds16(ga, As + ch * 1024);
            const char* gb = (const char*)W
                + ((size_t)(bn + row) * 1024 + kt * 64) * 2 + lslot * 16;
            gload_lds16(gb, Bs + ch * 1024);
        }
        __syncthreads();

#pragma unroll
        for (int kk = 0; kk < 2; ++kk) {
            const int cb = (kk * 32 + (l >> 4) * 8) * 2;   // byte col within row
            bf16x8 af[4], bfr[4];
#pragma unroll
            for (int m = 0; m < 4; m++)
                af[m] = *(const bf16x8*)(As + (wy * 64 + m * 16 + (l & 15)) * 128 + cb);
#pragma unroll
            for (int n = 0; n < 4; n++)
                bfr[n] = *(const bf16x8*)(Bs + (wx * 64 + n * 16 + (l & 15)) * 128 + cb);
#pragma unroll
            for (int m = 0; m < 4; m++)
#pragma unroll
                for (int n = 0; n < 4; n++)
                    acc[m][n] = __builtin_amdgcn_mfma_f32_16x16x32_bf16(
                        af[m], bfr[n], acc[m][n], 0, 0, 0);
        }
        __syncthreads();
    }

    // C/D layout: col = l&15, row = (l>>4)*4 + r
#pragma unroll
    for (int m = 0; m < 4; m++) {
        int grow0 = bm + wy * 64 + m * 16 + (l >> 4) * 4;
#pragma unroll
        for (int n = 0; n < 4; n++) {
            int gcol = bn + wx * 64 + n * 16 + (l & 15);
#pragma unroll
            for (int r = 0; r < 4; r++)
                storeC(&Cz[(size_t)(grow0 + r) * 1024 + gcol], acc[m][n][r]);
        }
    }
}

// ---------------------------------------------------------------------------
// Flash attention, causal. Q/K/V bf16 [B*T,1024] slabs, head h at col h*64.
// Block = (qtile 0..31, b*16+h). 4 waves x 16 q-rows, KVBLK=64.
// K read directly from global (L2-resident). V transposed into padded LDS.
// ---------------------------------------------------------------------------
__global__ __launch_bounds__(256) void attn_fwd(
    const u16* __restrict__ Q, const u16* __restrict__ K,
    const u16* __restrict__ V, u16* __restrict__ O)
{
    __shared__ __align__(16) u16 Vt[64][72];       // Vt[d][j] = V[j][d]
    __shared__ __align__(16) u16 Ps[4][16][72];    // per-wave P

    const int qt = blockIdx.x;
    const int bh = blockIdx.y;
    const int b = bh >> 4, h = bh & 15;
    const int tid = threadIdx.x, w = tid >> 6, l = tid & 63;
    const size_t base = (size_t)b * T_SEQ * 1024 + h * 64;

    // Q fragments for the whole KV loop. A-frag: row=l&15, k=(l>>4)*8+e
    const int qrow = qt * 64 + w * 16 + (l & 15);
    const u16* qp = Q + base + (size_t)qrow * 1024 + (l >> 4) * 8;
    bf16x8 qf[2];
    qf[0] = *(const bf16x8*)(qp);
    qf[1] = *(const bf16x8*)(qp + 32);

    f32x4 oacc[4];
#pragma unroll
    for (int n = 0; n < 4; n++) oacc[n] = (f32x4){0.f, 0.f, 0.f, 0.f};
    float mrun[4], lrun[4];
#pragma unroll
    for (int r = 0; r < 4; r++) { mrun[r] = NEG_BIG; lrun[r] = 0.f; }

    const int qg = qt * 64 + w * 16;               // wave's first global q row

    for (int kt = 0; kt <= qt; ++kt) {
        __syncthreads();    // protect Vt of previous iteration

        // ---- stage V transposed: Vt[d][j] = V[kt*64+j][d]
#pragma unroll
        for (int i = 0; i < 2; ++i) {
            int tk = tid + 256 * i;
            int jr = tk >> 3, dg = tk & 7;
            s16x8 vv = *(const s16x8*)(V + base + (size_t)(kt * 64 + jr) * 1024 + dg * 8);
#pragma unroll
            for (int e = 0; e < 8; e++)
                Vt[dg * 8 + e][jr] = (u16)vv[e];
        }
        __syncthreads();

        // ---- S = Q K^T, K B-frags straight from global (contiguous 16B)
        f32x4 s[4];
#pragma unroll
        for (int n = 0; n < 4; n++) s[n] = (f32x4){0.f, 0.f, 0.f, 0.f};
#pragma unroll
        for (int kk = 0; kk < 2; ++kk) {
#pragma unroll
            for (int nt = 0; nt < 4; ++nt) {
                bf16x8 kf = *(const bf16x8*)(K + base
                    + (size_t)(kt * 64 + nt * 16 + (l & 15)) * 1024
                    + kk * 32 + (l >> 4) * 8);
                s[nt] = __builtin_amdgcn_mfma_f32_16x16x32_bf16(qf[kk], kf, s[nt], 0, 0, 0);
            }
        }

        // ---- online softmax; lane holds rows (l>>4)*4+r, cols nt*16+(l&15)
        const int jb = kt * 64 + (l & 15);
#pragma unroll
        for (int r = 0; r < 4; ++r) {
            const int qrow_g = qg + (l >> 4) * 4 + r;
            float mt = NEG_BIG;
#pragma unroll
            for (int nt = 0; nt < 4; ++nt) {
                float v = (jb + nt * 16 > qrow_g) ? NEG_BIG : s[nt][r] * 0.125f;
                s[nt][r] = v;
                mt = fmaxf(mt, v);
            }
#pragma unroll
            for (int d = 1; d < 16; d <<= 1) mt = fmaxf(mt, __shfl_xor(mt, d));
            float mnew = fmaxf(mrun[r], mt);
            float alpha = __expf(mrun[r] - mnew);
            mrun[r] = mnew;
            float rs = 0.f;
#pragma unroll
            for (int nt = 0; nt < 4; ++nt) {
                float p = __expf(s[nt][r] - mnew);
                s[nt][r] = p;
                rs += p;
            }
#pragma unroll
            for (int d = 1; d < 16; d <<= 1) rs += __shfl_xor(rs, d);
            lrun[r] = lrun[r] * alpha + rs;
#pragma unroll
            for (int nt = 0; nt < 4; ++nt) oacc[nt][r] *= alpha;
        }

        // ---- P -> per-wave LDS (bf16)
#pragma unroll
        for (int nt = 0; nt < 4; ++nt)
#pragma unroll
            for (int r = 0; r < 4; ++r)
                Ps[w][(l >> 4) * 4 + r][nt * 16 + (l & 15)] = f2bf(s[nt][r]);

        // ---- O += P V (A-frag from Ps, B-frag from Vt; same-wave DS ordered)
#pragma unroll
        for (int kk = 0; kk < 2; ++kk) {
            bf16x8 pf = *(const bf16x8*)(&Ps[w][l & 15][kk * 32 + (l >> 4) * 8]);
#pragma unroll
            for (int nt = 0; nt < 4; ++nt) {
                bf16x8 vf = *(const bf16x8*)(&Vt[nt * 16 + (l & 15)][kk * 32 + (l >> 4) * 8]);
                oacc[nt] = __builtin_amdgcn_mfma_f32_16x16x32_bf16(pf, vf, oacc[nt], 0, 0, 0);
            }
        }
    }

    // ---- epilogue: O /= l
#pragma unroll
    for (int nt = 0; nt < 4; ++nt) {
        int gcol = h * 64 + nt * 16 + (l & 15);
#pragma unroll
        for (int r = 0; r < 4; ++r) {
            int row = qt * 64 + w * 16 + (l >> 4) * 4 + r;
            O[(size_t)b * T_SEQ * 1024 + (size_t)row * 1024 + gcol] = f2bf(oacc[nt][r] / lrun[r]);
        }
    }
}

// ---------------------------------------------------------------------------
extern "C" void kernel_launch(void* const* d_in, const int* in_sizes, int n_in,
                              void* d_out, int out_size, void* d_ws, size_t ws_size,
                              hipStream_t stream)
{
    (void)in_sizes; (void)n_in; (void)out_size; (void)ws_size;
    const float* x  = (const float*)d_in[0];
    const float* wq = (const float*)d_in[1];
    const float* wk = (const float*)d_in[2];
    const float* wv = (const float*)d_in[3];
    const float* wo = (const float*)d_in[4];
    float* out = (float*)d_out;

    char* ws = (char*)d_ws;
    u16* xb = (u16*)(ws);                    // x bf16, 8MB
    u16* wb = (u16*)(ws + (8u << 20));       // wq,wk,wv,wo bf16, 4 x 2MB
    u16* Kb = (u16*)(ws + (16u << 20));      // [4096,1024] bf16
    u16* Vb = (u16*)(ws + (24u << 20));
    u16* Ob = (u16*)(ws + (32u << 20));
    u16* Qb = (u16*)d_out;                   // Q bf16 in d_out's first 8MB

    dim3 blk(256);
    // f32 -> bf16
    cvt_f32_bf16<<<4096, blk, 0, stream>>>(x, xb, 1048576);
    cvt_f32_bf16<<<1024, blk, 0, stream>>>(wq, wb + 0u * 1048576u, 262144);
    cvt_f32_bf16<<<1024, blk, 0, stream>>>(wk, wb + 1u * 1048576u, 262144);
    cvt_f32_bf16<<<1024, blk, 0, stream>>>(wv, wb + 2u * 1048576u, 262144);
    cvt_f32_bf16<<<1024, blk, 0, stream>>>(wo, wb + 3u * 1048576u, 262144);

    // Q,K,V = x @ {wq,wk,wv}^T  (bf16 out)
    gemm_bt<u16><<<dim3(8, 32, 3), blk, 0, stream>>>(xb, wb, Qb, Kb, Vb);
    // causal flash attention
    attn_fwd<<<dim3(32, 32, 1), blk, 0, stream>>>(Qb, Kb, Vb, Ob);
    // out = O @ wo^T  (f32 out; overwrites d_out — Q is dead by now)
    gemm_bt<float><<<dim3(8, 32, 1), blk, 0, stream>>>(Ob, wb + 3u * 1048576u,
                                                       out, out, out);
}